// Round 6
// baseline (233.960 us; speedup 1.0000x reference)
//
#include <hip/hip_runtime.h>
#include <math.h>

#define NATOMS   1025
#define GSTRIDE  1040               // padded row stride (floats)
#define GELEMS   (1025*GSTRIDE)
#define NNZ      32
#define NBATCH   64
#define REGL     0.0067153485f      // softplus(-5) in fp32

// DPP cross-lane helpers (VALU-latency, no LDS). old=0, bound_ctrl=false ->
// invalid source lanes contribute 0 (safe: max over non-negatives / sum).
#define DPPF(x, ctrl) __int_as_float(__builtin_amdgcn_update_dpp(0, __float_as_int(x), (ctrl), 0xF, 0xF, false))

__device__ __forceinline__ float wave_max64(float x) {
    x = fmaxf(x, DPPF(x, 0x111));   // row_shr:1
    x = fmaxf(x, DPPF(x, 0x112));   // row_shr:2
    x = fmaxf(x, DPPF(x, 0x114));   // row_shr:4
    x = fmaxf(x, DPPF(x, 0x118));   // row_shr:8
    x = fmaxf(x, DPPF(x, 0x142));   // row_bcast:15
    x = fmaxf(x, DPPF(x, 0x143));   // row_bcast:31
    return __int_as_float(__builtin_amdgcn_readlane(__float_as_int(x), 63));
}
__device__ __forceinline__ float wave_sum64(float x) {
    x += DPPF(x, 0x111);
    x += DPPF(x, 0x112);
    x += DPPF(x, 0x114);
    x += DPPF(x, 0x118);
    x += DPPF(x, 0x142);
    x += DPPF(x, 0x143);
    return __int_as_float(__builtin_amdgcn_readlane(__float_as_int(x), 63));
}

// ---------------------------------------------------------------------------
// fused gram+projy. blockIdx.z < nsplit: gram (triangular bx<=by, 128x128 tile,
// 8x8/thread, split-K). blockIdx.z == nsplit: projy (64-atom x 16-batch tile).
// ---------------------------------------------------------------------------
__global__ __launch_bounds__(256)
void gramprojy_kernel(const float* __restrict__ X0, const float* __restrict__ y,
                      float* __restrict__ Gout, float* __restrict__ PY,
                      int kLen, int nsplit) {
    __shared__ float lds[8192];
    const int tid = threadIdx.x;

    if ((int)blockIdx.z < nsplit) {
        // ================= gram role =================
        const int bx = blockIdx.x, by = blockIdx.y, bz = blockIdx.z;
        if (by < bx) return;
        float* As = lds;            // [32][128]
        float* Bs = lds + 4096;     // [32][128]
        const int a0 = bx * 128, b0 = by * 128;
        float* __restrict__ Gp = Gout + (size_t)bz * GELEMS;
        const int tx = tid & 15;
        const int ty = tid >> 4;
        const int lr = tid >> 5;
        const int lc = (tid & 31) * 4;
        const bool aIn = (a0 + 128) <= 1024;
        const bool bIn = (b0 + 128) <= 1024;

        float acc[8][8];
#pragma unroll
        for (int m = 0; m < 8; ++m)
#pragma unroll
            for (int n = 0; n < 8; ++n) acc[m][n] = 0.0f;

        const int kBase = bz * kLen;
        for (int kc = 0; kc < kLen; kc += 32) {
#pragma unroll
            for (int rr = 0; rr < 4; ++rr) {
                const int r = lr + rr * 8;
                const int l = kBase + kc + r;
                if (aIn) {
                    *(float4*)&As[r * 128 + lc] = *(const float4*)&X0[(size_t)l * 1024 + a0 + lc];
                } else {
#pragma unroll
                    for (int k = 0; k < 4; ++k) {
                        const int col = a0 + lc + k;
                        As[r * 128 + lc + k] = (col < 1024) ? X0[(size_t)l * 1024 + col]
                                                            : (col == 1024 ? 1.0f : 0.0f);
                    }
                }
                if (bIn) {
                    *(float4*)&Bs[r * 128 + lc] = *(const float4*)&X0[(size_t)l * 1024 + b0 + lc];
                } else {
#pragma unroll
                    for (int k = 0; k < 4; ++k) {
                        const int col = b0 + lc + k;
                        Bs[r * 128 + lc + k] = (col < 1024) ? X0[(size_t)l * 1024 + col]
                                                            : (col == 1024 ? 1.0f : 0.0f);
                    }
                }
            }
            __syncthreads();
#pragma unroll 8
            for (int l = 0; l < 32; ++l) {
                float4 a01 = *(const float4*)&As[l * 128 + ty * 8];
                float4 a23 = *(const float4*)&As[l * 128 + ty * 8 + 4];
                float4 bA  = *(const float4*)&Bs[l * 128 + tx * 4];
                float4 bB  = *(const float4*)&Bs[l * 128 + 64 + tx * 4];
                float am[8] = {a01.x, a01.y, a01.z, a01.w, a23.x, a23.y, a23.z, a23.w};
                float bn[8] = {bA.x, bA.y, bA.z, bA.w, bB.x, bB.y, bB.z, bB.w};
#pragma unroll
                for (int m = 0; m < 8; ++m)
#pragma unroll
                    for (int n = 0; n < 8; ++n)
                        acc[m][n] += am[m] * bn[n];
            }
            __syncthreads();
        }

#pragma unroll
        for (int m = 0; m < 8; ++m) {
            const int a = a0 + ty * 8 + m;
            if (a >= NATOMS) continue;
            const int bAc = b0 + tx * 4;
            const int bBc = b0 + 64 + tx * 4;
            if (bAc < GSTRIDE) {
                *(float4*)&Gp[(size_t)a * GSTRIDE + bAc] =
                    make_float4(acc[m][0], acc[m][1], acc[m][2], acc[m][3]);
            }
            if (bBc < GSTRIDE) {
                *(float4*)&Gp[(size_t)a * GSTRIDE + bBc] =
                    make_float4(acc[m][4], acc[m][5], acc[m][6], acc[m][7]);
            }
        }
    } else {
        // ================= projy role =================
        const int pw = blockIdx.y * 9 + blockIdx.x;
        if (pw >= 68) return;
        const int a0 = (pw % 17) * 64;
        const int b0 = (pw / 17) * 16;
        float* Ds = lds;            // [32][64]
        float* Ys = lds + 2048;     // [32][17]
        const int tx = tid & 15;
        const int ty = tid >> 4;
        const bool aIn = (a0 + 64) <= 1024;

        float acc[4] = {0.0f, 0.0f, 0.0f, 0.0f};

        for (int kc = 0; kc < 1024; kc += 32) {
            {
                const int r  = tid >> 4;
                const int c4 = (tid & 15) * 4;
#pragma unroll
                for (int rr = 0; rr < 2; ++rr) {
                    const int row = r + rr * 16;
                    const int l = kc + row;
                    if (aIn) {
                        *(float4*)&Ds[row * 64 + c4] = *(const float4*)&X0[(size_t)l * 1024 + a0 + c4];
                    } else {
#pragma unroll
                        for (int k = 0; k < 4; ++k) {
                            const int col = a0 + c4 + k;
                            Ds[row * 64 + c4 + k] = (col < 1024) ? X0[(size_t)l * 1024 + col]
                                                                 : (col == 1024 ? 1.0f : 0.0f);
                        }
                    }
                }
            }
            for (int e = tid; e < 512; e += 256) {
                const int l = e & 31, bb = e >> 5;
                Ys[l * 17 + bb] = y[(size_t)(b0 + bb) * 1024 + kc + l];
            }
            __syncthreads();
#pragma unroll 8
            for (int l = 0; l < 32; ++l) {
                const float yv = Ys[l * 17 + ty];
                float4 dv = *(const float4*)&Ds[l * 64 + tx * 4];
                acc[0] += yv * dv.x; acc[1] += yv * dv.y;
                acc[2] += yv * dv.z; acc[3] += yv * dv.w;
            }
            __syncthreads();
        }
        const int a = a0 + tx * 4;
        if (a < GSTRIDE) {
            *(float4*)&PY[(size_t)(b0 + ty) * GSTRIDE + a] =
                make_float4(acc[0], acc[1], acc[2], acc[3]);
        }
    }
}

// ---------------------------------------------------------------------------
// combine: sum nsplit partials over upper tiles, write G[a][b] + mirror G[b][a]
// (exact symmetry), and diagG[a] = G[a][a].
// ---------------------------------------------------------------------------
__global__ __launch_bounds__(256)
void combine_kernel(const float* __restrict__ Gp, float* __restrict__ G,
                    float* __restrict__ diagG, int nsplit) {
    int tt = blockIdx.x, bx = 0;
    while (tt >= 9 - bx) { tt -= 9 - bx; ++bx; }
    const int by = bx + tt;
    const int yq = blockIdx.y;
    const int tid = threadIdx.x;
    for (int rep = 0; rep < 16; ++rep) {
        const int idx = yq * 4096 + rep * 256 + tid;
        const int r = idx >> 7, c = idx & 127;
        const int a = bx * 128 + r, b = by * 128 + c;
        if (a > 1024 || b > 1024) continue;
        float s = 0.0f;
        for (int z = 0; z < nsplit; ++z)
            s += Gp[(size_t)z * GELEMS + (size_t)a * GSTRIDE + b];
        G[(size_t)a * GSTRIDE + b] = s;
        G[(size_t)b * GSTRIDE + a] = s;
        if (a == b) diagG[a] = s;
    }
}

// ---------------------------------------------------------------------------
// omp: one wg/batch, 1024 threads (16 waves = 4/SIMD: latency hiding at 1 wg/CU).
// Thread tid owns atom tid (tid 1023 also owns atom 1024). 2 barriers/iter,
// DPP reductions, deferred rank-1 Ainv update (1 elem/thread).
// ---------------------------------------------------------------------------
__global__ __launch_bounds__(1024)
void omp_kernel(const float* __restrict__ G, const float* __restrict__ PY,
                const float* __restrict__ diagG,
                int* __restrict__ idxOut, float* __restrict__ wOut) {
    __shared__ float rowsLds[NNZ][GSTRIDE];   // 133,120 B, zero-init
    __shared__ float pyLds[1040];             // original y@D row
    __shared__ float diagLds[1040];
    __shared__ float Ainv[32][33];
    __shared__ float wv[32], rhs[32], uvb[32];
    __shared__ int   selIdx[32];
    __shared__ float redV[16];
    __shared__ int   redI[16];
    __shared__ float sc_dinv;

    const int b = blockIdx.x, tid = threadIdx.x;
    const int lane = tid & 63, wid = tid >> 6;

    // ---- init: zero everything the padded loops touch
    {
        float4 z4 = make_float4(0.f, 0.f, 0.f, 0.f);
        float4* rz = (float4*)rowsLds;
        for (int u = tid; u < NNZ * GSTRIDE / 4; u += 1024) rz[u] = z4;
        if (tid < 32) { wv[tid] = 0.f; rhs[tid] = 0.f; uvb[tid] = 0.f; }
        for (int u = tid; u < 32 * 33; u += 1024) ((float*)Ainv)[u] = 0.f;
        const float* pyg = PY + (size_t)b * GSTRIDE;
        pyLds[tid] = pyg[tid];
        if (tid < 16) pyLds[1024 + tid] = pyg[1024 + tid];
        diagLds[tid] = diagG[tid];
        if (tid == 0) diagLds[1024] = diagG[1024];
    }
    __syncthreads();

    for (int i = 0; i < NNZ; ++i) {
        // ---- deferred rank-1 Ainv update from iteration i-1 (1 elem/thread)
        if (i > 0) {
            const float dprev = sc_dinv;
            const int j = tid >> 5, k = tid & 31;
            Ainv[j][k] = fmaf(uvb[j] * uvb[k], dprev, Ainv[j][k]);
        }

        // ---- Phase A: proj recompute + local abs-argmax (atom tid; 1023 also 1024)
        float p  = pyLds[tid];
        float p2 = pyLds[1024];
        for (int jb = 0; jb < NNZ; jb += 8) {
            if (jb >= i) break;
#pragma unroll
            for (int jj = 0; jj < 8; ++jj) {
                const int j = jb + jj;                 // j >= i terms are exact 0
                const float wj = wv[j];
                p  = fmaf(-wj, rowsLds[j][tid],  p);
                p2 = fmaf(-wj, rowsLds[j][1024], p2);
            }
        }
        float best = fabsf(p); int bidx = tid;
        if (tid == 1023) {
            const float v = fabsf(p2);
            if (v > best) { best = v; bidx = 1024; }
        }

        // ---- wave argmax: DPP value max (exact), first-matching-lane index
        const float wmax = wave_max64(best);
        const unsigned long long mask = __ballot(best == wmax);
        const int fl = __ffsll((unsigned long long)mask) - 1;
        const int widx = __builtin_amdgcn_readlane(bidx, fl);
        if (lane == 0) { redV[wid] = wmax; redI[wid] = widx; }
        __syncthreads();                                     // (1)

        // winner, replicated identically on all threads (broadcast LDS reads)
        float bv_ = redV[0]; int sel = redI[0];
#pragma unroll
        for (int q = 1; q < 16; ++q) {
            if (redV[q] > bv_ || (redV[q] == bv_ && redI[q] < sel)) {
                bv_ = redV[q]; sel = redI[q];
            }
        }
        const float pysel = pyLds[sel];

        // ---- issue staging loads for row sel (consumed after the solve)
        float stg = 0.f, stg2 = 0.f;
        const float* __restrict__ grow = G + (size_t)sel * GSTRIDE;
        if (i < NNZ - 1) {
            stg = grow[tid];
            if (tid == 1023) stg2 = grow[1024];
        }

        // ---- solve (wave 0): border entirely from LDS (G symmetric)
        if (wid == 0) {
            float bvl = 0.0f, rl = 0.0f;
            if (lane < 32) { bvl = rowsLds[lane][sel]; rl = rhs[lane]; }
            const int lr_ = lane & 31;
            float u0 = 0.f, u1 = 0.f, u2 = 0.f, u3 = 0.f;
#pragma unroll
            for (int m = 0; m < 32; m += 4) {            // rows >= i are 0
                u0 = fmaf(Ainv[lr_][m + 0], rowsLds[m + 0][sel], u0);
                u1 = fmaf(Ainv[lr_][m + 1], rowsLds[m + 1][sel], u1);
                u2 = fmaf(Ainv[lr_][m + 2], rowsLds[m + 2][sel], u2);
                u3 = fmaf(Ainv[lr_][m + 3], rowsLds[m + 3][sel], u3);
            }
            const float uacc = (u0 + u1) + (u2 + u3);
            const float t = wave_sum64(bvl * uacc);      // lanes>=32 contribute 0
            const float s = wave_sum64(rl * uacc);
            const float dinv = 1.0f / (diagLds[sel] + REGL - t);
            const float beta = dinv * (pysel - s);
            if (lane < 32) {
                uvb[lane] = (lane == i) ? -1.0f : uacc;  // u-bar for deferred rank-1
                wv[lane]  = (lane == i) ? beta  : wv[lane] - uacc * beta;
            }
            if (lane == 0) { selIdx[i] = sel; rhs[i] = pysel; sc_dinv = dinv; }
        }

        // ---- stage row into LDS (global loads were in flight under the solve)
        if (i < NNZ - 1) {
            rowsLds[i][tid] = stg;
            if (tid == 1023) rowsLds[i][1024] = stg2;
        }
        __syncthreads();                                     // (2)
    }

    if (tid < NNZ) {
        idxOut[b * NNZ + tid] = selIdx[tid];
        wOut[b * NNZ + tid] = wv[tid];
    }
}

// ---------------------------------------------------------------------------
// recon: out[b][l] = sum_a X[b][l][a]*W[b][a] + W[b][1024]
// W built dense in LDS with sequential last-wins scatter (matches .at[].set)
// ---------------------------------------------------------------------------
__global__ __launch_bounds__(256)
void recon_kernel(const float* __restrict__ X, const int* __restrict__ idxIn,
                  const float* __restrict__ wIn, float* __restrict__ out) {
    __shared__ float4 Wd4[260];
    const int b = blockIdx.x >> 3, chunk = blockIdx.x & 7;
    const int tid = threadIdx.x, lane = tid & 63, wid = tid >> 6;
    float* Wd = (float*)Wd4;
    for (int u = tid; u < 1040; u += 256) Wd[u] = 0.0f;
    __syncthreads();
    if (tid == 0) {
#pragma unroll
        for (int i = 0; i < NNZ; ++i) Wd[idxIn[b * NNZ + i]] = wIn[b * NNZ + i];
    }
    __syncthreads();
    const float wOne = Wd[1024];
    const float* Xb = X + (size_t)b * 1024 * 1024;

    for (int rr = wid; rr < 128; rr += 4) {
        const int r = chunk * 128 + rr;
        const float4* xr = (const float4*)(Xb + (size_t)r * 1024);
        float acc = 0.0f;
#pragma unroll
        for (int q = 0; q < 4; ++q) {
            float4 x = xr[q * 64 + lane];
            float4 w = Wd4[q * 64 + lane];
            acc += x.x * w.x + x.y * w.y + x.z * w.z + x.w * w.w;
        }
        for (int off = 32; off; off >>= 1) acc += __shfl_xor(acc, off);
        if (lane == 0) out[(size_t)b * 1024 + r] = acc + wOne;
    }
}

// ---------------------------------------------------------------------------
extern "C" void kernel_launch(void* const* d_in, const int* in_sizes, int n_in,
                              void* d_out, int out_size, void* d_ws, size_t ws_size,
                              hipStream_t stream) {
    const float* X = (const float*)d_in[0];
    const float* y = (const float*)d_in[1];
    float* out = (float*)d_out;
    float* ws = (float*)d_ws;

    const size_t need4 = ((size_t)GELEMS * 5 + 64 * GSTRIDE + NBATCH * NNZ * 2 + 2048) * sizeof(float);
    const int nsplit = (ws_size >= need4) ? 4 : 1;
    const int kLen = 1024 / nsplit;

    float* Gp = ws;
    float* G  = ws + (size_t)GELEMS * nsplit;
    float* PY = G + (size_t)GELEMS;
    float* wOut = PY + (size_t)64 * GSTRIDE;
    int* idxOut = (int*)(wOut + NBATCH * NNZ);
    float* diagG = (float*)(idxOut + NBATCH * NNZ);

    gramprojy_kernel<<<dim3(9, 9, nsplit + 1), 256, 0, stream>>>(X, y, Gp, PY, kLen, nsplit);
    combine_kernel<<<dim3(45, 4), 256, 0, stream>>>(Gp, G, diagG, nsplit);
    omp_kernel<<<NBATCH, 1024, 0, stream>>>(G, PY, diagG, idxOut, wOut);
    recon_kernel<<<NBATCH * 8, 256, 0, stream>>>(X, idxOut, wOut, out);
}

// Round 8
// 218.745 us; speedup vs baseline: 1.0696x; 1.0696x over previous
//
#include <hip/hip_runtime.h>
#include <math.h>

#define NATOMS   1025
#define GSTRIDE  1040               // padded row stride (floats)
#define GELEMS   (1025*GSTRIDE)
#define NNZ      32
#define NBATCH   64
#define REGL     0.0067153485f      // softplus(-5) in fp32

// DPP cross-lane helpers (VALU-latency, no LDS). old=0, bound_ctrl=false ->
// invalid source lanes contribute 0 (safe: max over non-negatives / sum).
#define DPPF(x, ctrl) __int_as_float(__builtin_amdgcn_update_dpp(0, __float_as_int(x), (ctrl), 0xF, 0xF, false))

__device__ __forceinline__ float wave_max64(float x) {
    x = fmaxf(x, DPPF(x, 0x111));   // row_shr:1
    x = fmaxf(x, DPPF(x, 0x112));   // row_shr:2
    x = fmaxf(x, DPPF(x, 0x114));   // row_shr:4
    x = fmaxf(x, DPPF(x, 0x118));   // row_shr:8
    x = fmaxf(x, DPPF(x, 0x142));   // row_bcast:15
    x = fmaxf(x, DPPF(x, 0x143));   // row_bcast:31
    return __int_as_float(__builtin_amdgcn_readlane(__float_as_int(x), 63));
}
__device__ __forceinline__ float wave_sum64(float x) {
    x += DPPF(x, 0x111);
    x += DPPF(x, 0x112);
    x += DPPF(x, 0x114);
    x += DPPF(x, 0x118);
    x += DPPF(x, 0x142);
    x += DPPF(x, 0x143);
    return __int_as_float(__builtin_amdgcn_readlane(__float_as_int(x), 63));
}

// ---------------------------------------------------------------------------
// fused gram+projy. blockIdx.z < nsplit: gram (triangular bx<=by, 128x128 tile,
// 8x8/thread, split-K). blockIdx.z == nsplit: projy (64-atom x 16-batch tile).
// ---------------------------------------------------------------------------
__global__ __launch_bounds__(256)
void gramprojy_kernel(const float* __restrict__ X0, const float* __restrict__ y,
                      float* __restrict__ Gout, float* __restrict__ PY,
                      int kLen, int nsplit) {
    __shared__ float lds[8192];
    const int tid = threadIdx.x;

    if ((int)blockIdx.z < nsplit) {
        // ================= gram role =================
        const int bx = blockIdx.x, by = blockIdx.y, bz = blockIdx.z;
        if (by < bx) return;
        float* As = lds;            // [32][128]
        float* Bs = lds + 4096;     // [32][128]
        const int a0 = bx * 128, b0 = by * 128;
        float* __restrict__ Gp = Gout + (size_t)bz * GELEMS;
        const int tx = tid & 15;
        const int ty = tid >> 4;
        const int lr = tid >> 5;
        const int lc = (tid & 31) * 4;
        const bool aIn = (a0 + 128) <= 1024;
        const bool bIn = (b0 + 128) <= 1024;

        float acc[8][8];
#pragma unroll
        for (int m = 0; m < 8; ++m)
#pragma unroll
            for (int n = 0; n < 8; ++n) acc[m][n] = 0.0f;

        const int kBase = bz * kLen;
        for (int kc = 0; kc < kLen; kc += 32) {
#pragma unroll
            for (int rr = 0; rr < 4; ++rr) {
                const int r = lr + rr * 8;
                const int l = kBase + kc + r;
                if (aIn) {
                    *(float4*)&As[r * 128 + lc] = *(const float4*)&X0[(size_t)l * 1024 + a0 + lc];
                } else {
#pragma unroll
                    for (int k = 0; k < 4; ++k) {
                        const int col = a0 + lc + k;
                        As[r * 128 + lc + k] = (col < 1024) ? X0[(size_t)l * 1024 + col]
                                                            : (col == 1024 ? 1.0f : 0.0f);
                    }
                }
                if (bIn) {
                    *(float4*)&Bs[r * 128 + lc] = *(const float4*)&X0[(size_t)l * 1024 + b0 + lc];
                } else {
#pragma unroll
                    for (int k = 0; k < 4; ++k) {
                        const int col = b0 + lc + k;
                        Bs[r * 128 + lc + k] = (col < 1024) ? X0[(size_t)l * 1024 + col]
                                                            : (col == 1024 ? 1.0f : 0.0f);
                    }
                }
            }
            __syncthreads();
#pragma unroll 8
            for (int l = 0; l < 32; ++l) {
                float4 a01 = *(const float4*)&As[l * 128 + ty * 8];
                float4 a23 = *(const float4*)&As[l * 128 + ty * 8 + 4];
                float4 bA  = *(const float4*)&Bs[l * 128 + tx * 4];
                float4 bB  = *(const float4*)&Bs[l * 128 + 64 + tx * 4];
                float am[8] = {a01.x, a01.y, a01.z, a01.w, a23.x, a23.y, a23.z, a23.w};
                float bn[8] = {bA.x, bA.y, bA.z, bA.w, bB.x, bB.y, bB.z, bB.w};
#pragma unroll
                for (int m = 0; m < 8; ++m)
#pragma unroll
                    for (int n = 0; n < 8; ++n)
                        acc[m][n] += am[m] * bn[n];
            }
            __syncthreads();
        }

#pragma unroll
        for (int m = 0; m < 8; ++m) {
            const int a = a0 + ty * 8 + m;
            if (a >= NATOMS) continue;
            const int bAc = b0 + tx * 4;
            const int bBc = b0 + 64 + tx * 4;
            if (bAc < GSTRIDE) {
                *(float4*)&Gp[(size_t)a * GSTRIDE + bAc] =
                    make_float4(acc[m][0], acc[m][1], acc[m][2], acc[m][3]);
            }
            if (bBc < GSTRIDE) {
                *(float4*)&Gp[(size_t)a * GSTRIDE + bBc] =
                    make_float4(acc[m][4], acc[m][5], acc[m][6], acc[m][7]);
            }
        }
    } else {
        // ================= projy role =================
        const int pw = blockIdx.y * 9 + blockIdx.x;
        if (pw >= 68) return;
        const int a0 = (pw % 17) * 64;
        const int b0 = (pw / 17) * 16;
        float* Ds = lds;            // [32][64]
        float* Ys = lds + 2048;     // [32][17]
        const int tx = tid & 15;
        const int ty = tid >> 4;
        const bool aIn = (a0 + 64) <= 1024;

        float acc[4] = {0.0f, 0.0f, 0.0f, 0.0f};

        for (int kc = 0; kc < 1024; kc += 32) {
            {
                const int r  = tid >> 4;
                const int c4 = (tid & 15) * 4;
#pragma unroll
                for (int rr = 0; rr < 2; ++rr) {
                    const int row = r + rr * 16;
                    const int l = kc + row;
                    if (aIn) {
                        *(float4*)&Ds[row * 64 + c4] = *(const float4*)&X0[(size_t)l * 1024 + a0 + c4];
                    } else {
#pragma unroll
                        for (int k = 0; k < 4; ++k) {
                            const int col = a0 + c4 + k;
                            Ds[row * 64 + c4 + k] = (col < 1024) ? X0[(size_t)l * 1024 + col]
                                                                 : (col == 1024 ? 1.0f : 0.0f);
                        }
                    }
                }
            }
            for (int e = tid; e < 512; e += 256) {
                const int l = e & 31, bb = e >> 5;
                Ys[l * 17 + bb] = y[(size_t)(b0 + bb) * 1024 + kc + l];
            }
            __syncthreads();
#pragma unroll 8
            for (int l = 0; l < 32; ++l) {
                const float yv = Ys[l * 17 + ty];
                float4 dv = *(const float4*)&Ds[l * 64 + tx * 4];
                acc[0] += yv * dv.x; acc[1] += yv * dv.y;
                acc[2] += yv * dv.z; acc[3] += yv * dv.w;
            }
            __syncthreads();
        }
        const int a = a0 + tx * 4;
        if (a < GSTRIDE) {
            *(float4*)&PY[(size_t)(b0 + ty) * GSTRIDE + a] =
                make_float4(acc[0], acc[1], acc[2], acc[3]);
        }
    }
}

// ---------------------------------------------------------------------------
// combine: sum nsplit partials over upper tiles, write G[a][b] + mirror G[b][a]
// (exact symmetry), and diagG[a] = G[a][a].
// ---------------------------------------------------------------------------
__global__ __launch_bounds__(256)
void combine_kernel(const float* __restrict__ Gp, float* __restrict__ G,
                    float* __restrict__ diagG, int nsplit) {
    int tt = blockIdx.x, bx = 0;
    while (tt >= 9 - bx) { tt -= 9 - bx; ++bx; }
    const int by = bx + tt;
    const int yq = blockIdx.y;
    const int tid = threadIdx.x;
    for (int rep = 0; rep < 16; ++rep) {
        const int idx = yq * 4096 + rep * 256 + tid;
        const int r = idx >> 7, c = idx & 127;
        const int a = bx * 128 + r, b = by * 128 + c;
        if (a > 1024 || b > 1024) continue;
        float s = 0.0f;
        for (int z = 0; z < nsplit; ++z)
            s += Gp[(size_t)z * GELEMS + (size_t)a * GSTRIDE + b];
        G[(size_t)a * GSTRIDE + b] = s;
        G[(size_t)b * GSTRIDE + a] = s;
        if (a == b) diagG[a] = s;
    }
}

// ---------------------------------------------------------------------------
// omp: one wg/batch, 512 threads (8 waves). 2 barriers/iter.
// Thread tid owns atoms 2tid,2tid+1 (tid 511 also atom 1024); proj lives in
// registers and is updated incrementally: proj += beta * sum_j uvb[j]*rows[j]
// (uvb[i] = -1, row i taken ONLY from the in-flight registers; rowsLds[i] is
// staged AFTER the proj update so the unroll-overshoot terms j in [i, jb+8)
// read exact zeros -- staging it earlier double-counts G_i [R7 bug]).
// The G-row global load is issued right after the winner is known and
// completes UNDER the wave-0 solve.
// ---------------------------------------------------------------------------
__global__ __launch_bounds__(512)
void omp_kernel(const float* __restrict__ G, const float* __restrict__ PY,
                const float* __restrict__ diagG,
                int* __restrict__ idxOut, float* __restrict__ wOut) {
    __shared__ float rowsLds[NNZ][GSTRIDE];   // 133,120 B, zero-init
    __shared__ float pyLds[1040];
    __shared__ float diagLds[1040];
    __shared__ float Ainv[32][33];
    __shared__ float wv[32], rhs[32], uvb[32];
    __shared__ int   selIdx[32];
    __shared__ float redV[8];
    __shared__ int   redI[8];
    __shared__ float sc_dinv;

    const int b = blockIdx.x, tid = threadIdx.x;
    const int lane = tid & 63, wid = tid >> 6;

    // ---- init: zero everything the padded loops touch
    {
        float4 z4 = make_float4(0.f, 0.f, 0.f, 0.f);
        float4* rz = (float4*)rowsLds;
        for (int u = tid; u < NNZ * GSTRIDE / 4; u += 512) rz[u] = z4;
        if (tid < 32) { wv[tid] = 0.f; rhs[tid] = 0.f; uvb[tid] = 0.f; }
        for (int u = tid; u < 32 * 33; u += 512) ((float*)Ainv)[u] = 0.f;
        const float* pyg = PY + (size_t)b * GSTRIDE;
        for (int u = tid; u < 1040; u += 512) pyLds[u] = pyg[u];
        for (int u = tid; u < 1025; u += 512) diagLds[u] = diagG[u];
    }
    __syncthreads();

    // ---- registers: proj for atoms 2tid, 2tid+1 (+1024 on tid 511)
    float p0 = pyLds[2 * tid], p1 = pyLds[2 * tid + 1];
    float p2 = (tid == 511) ? pyLds[1024] : 0.0f;

    // ---- prologue argmax on |py|
    {
        float best = fabsf(p0); int bidx = 2 * tid;
        { float v = fabsf(p1); if (v > best) { best = v; bidx = 2 * tid + 1; } }
        if (tid == 511) { float v = fabsf(p2); if (v > best) { best = v; bidx = 1024; } }
        const float wmax = wave_max64(best);
        const unsigned long long mask = __ballot(best == wmax);
        const int fl = __ffsll((unsigned long long)mask) - 1;
        const int widx = __builtin_amdgcn_readlane(bidx, fl);
        if (lane == 0) { redV[wid] = wmax; redI[wid] = widx; }
    }
    __syncthreads();                                         // barA

    for (int i = 0; i < NNZ; ++i) {
        // ---- winner, replicated identically on all threads
        float bv_ = redV[0]; int sel = redI[0];
#pragma unroll
        for (int q = 1; q < 8; ++q) {
            if (redV[q] > bv_ || (redV[q] == bv_ && redI[q] < sel)) {
                bv_ = redV[q]; sel = redI[q];
            }
        }
        const float pysel = pyLds[sel];

        // ---- issue G-row load NOW (completes under the solve)
        float2 rv = make_float2(0.f, 0.f);
        float rv2 = 0.f;
        const float* __restrict__ grow = G + (size_t)sel * GSTRIDE;
        if (i < NNZ - 1) {
            rv = *(const float2*)(grow + 2 * tid);
            if (tid == 511) rv2 = grow[1024];
        }

        // ---- solve (wave 0): border from rowsLds columns (G symmetric; only
        //      rows j<i needed -> row sel can still be in flight)
        if (wid == 0) {
            float bvl = 0.0f, rl = 0.0f;
            if (lane < 32) { bvl = rowsLds[lane][sel]; rl = rhs[lane]; }
            const int lr_ = lane & 31;
            float u0 = 0.f, u1 = 0.f, u2 = 0.f, u3 = 0.f;
#pragma unroll
            for (int m = 0; m < 32; m += 4) {            // rows >= i are 0
                u0 = fmaf(Ainv[lr_][m + 0], rowsLds[m + 0][sel], u0);
                u1 = fmaf(Ainv[lr_][m + 1], rowsLds[m + 1][sel], u1);
                u2 = fmaf(Ainv[lr_][m + 2], rowsLds[m + 2][sel], u2);
                u3 = fmaf(Ainv[lr_][m + 3], rowsLds[m + 3][sel], u3);
            }
            const float uacc = (u0 + u1) + (u2 + u3);
            const float t = wave_sum64(bvl * uacc);      // lanes>=32 contribute 0
            const float s = wave_sum64(rl * uacc);
            const float dinv = 1.0f / (diagLds[sel] + REGL - t);
            const float beta = dinv * (pysel - s);
            if (lane < 32) {
                uvb[lane] = (lane == i) ? -1.0f : uacc;
                wv[lane]  = (lane == i) ? beta  : wv[lane] - uacc * beta;
            }
            if (lane == 0) { selIdx[i] = sel; rhs[i] = pysel; sc_dinv = dinv; }
        }
        __syncthreads();                                     // barB
        if (i == NNZ - 1) break;

        // ---- deferred rank-1 Ainv update (2 elems/thread, exact cover)
        {
            const float dcur = sc_dinv;
            const int e0 = 2 * tid, j0 = e0 >> 5, k0 = e0 & 31;
            Ainv[j0][k0] = fmaf(uvb[j0] * uvb[k0], dcur, Ainv[j0][k0]);
            const int e1 = 2 * tid + 1, j1 = e1 >> 5, k1 = e1 & 31;
            Ainv[j1][k1] = fmaf(uvb[j1] * uvb[k1], dcur, Ainv[j1][k1]);
        }

        // ---- incremental proj update: p += beta * sum_{j<=i} uvb[j]*rows[j]
        //      j=i term ONLY via registers (uvb[i] = -1); rowsLds[i] is still
        //      all-zero here, so unroll overshoot j>=i contributes exact 0.
        const float beta = wv[i];
        float z0 = -rv.x, z1 = -rv.y, z2 = -rv2;
        for (int jb = 0; jb < NNZ; jb += 8) {
            if (jb >= i) break;
#pragma unroll
            for (int jj = 0; jj < 8; ++jj) {
                const int j = jb + jj;                   // j >= i terms are 0
                const float uj = uvb[j];
                z0 = fmaf(uj, rowsLds[j][2 * tid],     z0);
                z1 = fmaf(uj, rowsLds[j][2 * tid + 1], z1);
                if (tid == 511) z2 = fmaf(uj, rowsLds[j][1024], z2);
            }
        }
        p0 = fmaf(beta, z0, p0);
        p1 = fmaf(beta, z1, p1);
        if (tid == 511) p2 = fmaf(beta, z2, p2);

        // ---- NOW stage row i into LDS (after proj reads; before barA so the
        //      next iteration's solve sees it)
        rowsLds[i][2 * tid]     = rv.x;
        rowsLds[i][2 * tid + 1] = rv.y;
        if (tid == 511) rowsLds[i][1024] = rv2;

        // ---- abs-argmax (exact first-index tie-break)
        {
            float best = fabsf(p0); int bidx = 2 * tid;
            { float v = fabsf(p1); if (v > best) { best = v; bidx = 2 * tid + 1; } }
            if (tid == 511) { float v = fabsf(p2); if (v > best) { best = v; bidx = 1024; } }
            const float wmax = wave_max64(best);
            const unsigned long long mask = __ballot(best == wmax);
            const int fl = __ffsll((unsigned long long)mask) - 1;
            const int widx = __builtin_amdgcn_readlane(bidx, fl);
            if (lane == 0) { redV[wid] = wmax; redI[wid] = widx; }
        }
        __syncthreads();                                     // barA
    }

    if (tid < NNZ) {
        idxOut[b * NNZ + tid] = selIdx[tid];
        wOut[b * NNZ + tid] = wv[tid];
    }
}

// ---------------------------------------------------------------------------
// recon: out[b][l] = sum_a X[b][l][a]*W[b][a] + W[b][1024]
// W built dense in LDS with sequential last-wins scatter (matches .at[].set)
// ---------------------------------------------------------------------------
__global__ __launch_bounds__(256)
void recon_kernel(const float* __restrict__ X, const int* __restrict__ idxIn,
                  const float* __restrict__ wIn, float* __restrict__ out) {
    __shared__ float4 Wd4[260];
    const int b = blockIdx.x >> 3, chunk = blockIdx.x & 7;
    const int tid = threadIdx.x, lane = tid & 63, wid = tid >> 6;
    float* Wd = (float*)Wd4;
    for (int u = tid; u < 1040; u += 256) Wd[u] = 0.0f;
    __syncthreads();
    if (tid == 0) {
#pragma unroll
        for (int i = 0; i < NNZ; ++i) Wd[idxIn[b * NNZ + i]] = wIn[b * NNZ + i];
    }
    __syncthreads();
    const float wOne = Wd[1024];
    const float* Xb = X + (size_t)b * 1024 * 1024;

    for (int rr = wid; rr < 128; rr += 4) {
        const int r = chunk * 128 + rr;
        const float4* xr = (const float4*)(Xb + (size_t)r * 1024);
        float acc = 0.0f;
#pragma unroll
        for (int q = 0; q < 4; ++q) {
            float4 x = xr[q * 64 + lane];
            float4 w = Wd4[q * 64 + lane];
            acc += x.x * w.x + x.y * w.y + x.z * w.z + x.w * w.w;
        }
        acc = wave_sum64(acc);
        if (lane == 0) out[(size_t)b * 1024 + r] = acc + wOne;
    }
}

// ---------------------------------------------------------------------------
extern "C" void kernel_launch(void* const* d_in, const int* in_sizes, int n_in,
                              void* d_out, int out_size, void* d_ws, size_t ws_size,
                              hipStream_t stream) {
    const float* X = (const float*)d_in[0];
    const float* y = (const float*)d_in[1];
    float* out = (float*)d_out;
    float* ws = (float*)d_ws;

    const size_t need4 = ((size_t)GELEMS * 5 + 64 * GSTRIDE + NBATCH * NNZ * 2 + 2048) * sizeof(float);
    const int nsplit = (ws_size >= need4) ? 4 : 1;
    const int kLen = 1024 / nsplit;

    float* Gp = ws;
    float* G  = ws + (size_t)GELEMS * nsplit;
    float* PY = G + (size_t)GELEMS;
    float* wOut = PY + (size_t)64 * GSTRIDE;
    int* idxOut = (int*)(wOut + NBATCH * NNZ);
    float* diagG = (float*)(idxOut + NBATCH * NNZ);

    gramprojy_kernel<<<dim3(9, 9, nsplit + 1), 256, 0, stream>>>(X, y, Gp, PY, kLen, nsplit);
    combine_kernel<<<dim3(45, 4), 256, 0, stream>>>(Gp, G, diagG, nsplit);
    omp_kernel<<<NBATCH, 512, 0, stream>>>(G, PY, diagG, idxOut, wOut);
    recon_kernel<<<NBATCH * 8, 256, 0, stream>>>(X, idxOut, wOut, out);
}